// Round 1
// baseline (5216.382 us; speedup 1.0000x reference)
//
#include <hip/hip_runtime.h>
#include <math.h>

// Fused Conv2d(3x3, VALID, NCHW/OIHW) + bias + tanh-GELU + global mean.
// x: (64, 64, 128, 128) fp32, weight: (256, 64, 3, 3) fp32, bias: (256,)
// out: (64, 256) fp32.
//
// Block = one (n, co-group of 8). 64 * 32 = 2048 blocks, 256 threads.
// Threads map to a 2-row x 128-col strip of output pixels; loop over 63
// row-pairs. Weights are read with wave-uniform addresses -> scalar loads
// (s_load) via the constant cache; x reads are coalesced vector loads served
// by L1 (each 2KB x row reused 9x within a ci iteration). Conv accumulators,
// GELU, and the running spatial sum all live in registers; one LDS tree
// reduction per block at the very end.

#define CI 64
#define CO 256
#define HH 128
#define WW 128
#define HO 126
#define WO 126
#define COG 8

__global__ __launch_bounds__(256, 4)
void conv_gelu_mean_kernel(const float* __restrict__ x,
                           const float* __restrict__ wgt,
                           const float* __restrict__ bias,
                           float* __restrict__ out)
{
    const int bx  = blockIdx.x;
    const int n   = bx >> 5;        // 32 co-groups per image
    const int g   = bx & 31;
    const int co0 = g * COG;

    const int tid    = threadIdx.x;
    const int rowsel = tid >> 7;    // 0: first row of pair, 1: second
    const int w      = tid & 127;
    const bool active = (w < WO);
    const int wl     = active ? w : 0;   // clamp so inactive lanes stay in-bounds

    const float* xn = x + (size_t)n * CI * HH * WW;

    float gsum[COG];
#pragma unroll
    for (int c = 0; c < COG; ++c) gsum[c] = 0.f;

    float bia[COG];
#pragma unroll
    for (int c = 0; c < COG; ++c) bia[c] = bias[co0 + c];   // uniform -> s_load

    for (int h = 0; h < HO; h += 2) {
        const int hr = h + rowsel;          // output row of this thread
        float acc[COG];
#pragma unroll
        for (int c = 0; c < COG; ++c) acc[c] = 0.f;

        const float* xp = xn + hr * WW + wl;
        for (int ci = 0; ci < CI; ++ci) {
            float xv[9];
#pragma unroll
            for (int kh = 0; kh < 3; ++kh)
#pragma unroll
                for (int kw = 0; kw < 3; ++kw)
                    xv[kh * 3 + kw] = xp[kh * WW + kw];

            const float* wp = wgt + (size_t)co0 * CI * 9 + ci * 9;  // uniform base
#pragma unroll
            for (int c = 0; c < COG; ++c) {
#pragma unroll
                for (int k = 0; k < 9; ++k)
                    acc[c] = fmaf(xv[k], wp[c * CI * 9 + k], acc[c]); // s_load weight
            }
            xp += HH * WW;
        }

        if (active) {
#pragma unroll
            for (int c = 0; c < COG; ++c) {
                float y = acc[c] + bia[c];
                // tanh-approximate GELU (matches jax.nn.gelu approximate=True)
                float t = tanhf(0.7978845608028654f * (y + 0.044715f * y * y * y));
                gsum[c] += 0.5f * y * (1.f + t);
            }
        }
    }

    // Per-block reduction: 256 threads -> 8 outputs (n, co0..co0+7).
    __shared__ float red[256];
#pragma unroll 1
    for (int c = 0; c < COG; ++c) {
        red[tid] = gsum[c];
        __syncthreads();
        for (int s = 128; s > 0; s >>= 1) {
            if (tid < s) red[tid] += red[tid + s];
            __syncthreads();
        }
        if (tid == 0) out[n * CO + co0 + c] = red[0] * (1.f / (HO * WO));
        __syncthreads();
    }
}

extern "C" void kernel_launch(void* const* d_in, const int* in_sizes, int n_in,
                              void* d_out, int out_size, void* d_ws, size_t ws_size,
                              hipStream_t stream) {
    const float* x  = (const float*)d_in[0];
    const float* wg = (const float*)d_in[1];
    const float* bi = (const float*)d_in[2];
    float* out = (float*)d_out;
    conv_gelu_mean_kernel<<<dim3(64 * 32), dim3(256), 0, stream>>>(x, wg, bi, out);
}

// Round 2
// 882.058 us; speedup vs baseline: 5.9139x; 5.9139x over previous
//
#include <hip/hip_runtime.h>
#include <math.h>

// Implicit-GEMM conv3x3(64->256, VALID) + bias + tanh-GELU + spatial mean,
// bf16 MFMA (f32_16x16x32_bf16), fp32 accumulate.
//
// Decomposition: conv = sum over 9 taps of GEMM  W_tap[co,ci] * X_shift[ci,pix].
// Block = one (n, h): 256 co x 128 pixels (w 0..127; 126,127 masked), K = 576.
// x staged fp32->bf16 into LDS transposed to [row3][col][ci(+pad)] so each
// B-fragment (8 contiguous ci) is one ds_read_b128. Weights pre-transformed
// once per launch into ws as bf16 Wb[tap][co][ci] so each A-fragment is one
// 16B global load (288 KB total, L2-resident, reused by all 8064 blocks).
// Epilogue: bias + GELU(y)=y*sigmoid(2z) (1 exp + 1 rcp), masked pixel sum,
// 16-lane shuffle reduce, atomicAdd into pre-zeroed out (mean over 126*126).

typedef __attribute__((ext_vector_type(8))) short short8;
typedef __attribute__((ext_vector_type(4))) float floatx4;
typedef __attribute__((ext_vector_type(4))) unsigned int uintx4;

#define HO 126
#define CIP 40   // padded ci stride (bf16 elems): 80 B -> 16B-aligned b128, bank step 20 (conflict-free reads)

__device__ __forceinline__ unsigned short f2bf(float f) {
    unsigned int u = __float_as_uint(f);
    u = (u + 0x7FFFu + ((u >> 16) & 1u)) >> 16;   // RNE
    return (unsigned short)u;
}

__device__ __forceinline__ float gelu_t(float y) {
    // gelu(y) = y * sigmoid(2*0.7978845608*(y + 0.044715 y^3))
    float p = __builtin_fmaf(0.044715f, y * y, 1.0f);
    float z2 = -2.3022084f * y * p;               // -(2*0.79788456*log2 e) * y * p
    float e = exp2f(z2);
    return y * __builtin_amdgcn_rcpf(1.0f + e);   // y*sigmoid; large |y| -> 0/identity, no NaN
}

__global__ __launch_bounds__(256)
void prep_kernel(const float* __restrict__ wgt, float* __restrict__ out,
                 unsigned short* __restrict__ wb) {
    int g = blockIdx.x * 256 + threadIdx.x;
    if (g < 64 * 256) out[g] = 0.f;               // zero the atomic target
    if (g < 147456) {                             // 9*256*64
        int ci = g & 63;
        int co = (g >> 6) & 255;
        int tap = g >> 14;
        wb[g] = f2bf(wgt[(co * 64 + ci) * 9 + tap]);  // W[co][ci][kh][kw] -> Wb[tap][co][ci]
    }
}

__global__ __launch_bounds__(256, 2)
void conv_kernel(const float* __restrict__ x, const float* __restrict__ bias,
                 const unsigned short* __restrict__ wb, float* __restrict__ out) {
    __shared__ unsigned short xs[3][130][CIP];    // 31.2 KB

    const int bx = blockIdx.x;
    const int n = bx / HO;
    const int h = bx % HO;
    const int tid = threadIdx.x;
    const int lane = tid & 63;
    const int wave = tid >> 6;
    const int li = lane & 15;
    const int quad = lane >> 4;
    const int coBase = wave * 64;                 // wave tile: 64 co x 128 pix

    floatx4 acc[32];                              // [cf 0..3][pf 0..7]
#pragma unroll
    for (int i = 0; i < 32; ++i) acc[i] = (floatx4){0.f, 0.f, 0.f, 0.f};

    const int col = tid & 127;
    const int half = tid >> 7;
    const float* xg = x + ((size_t)n * 64) * 16384 + h * 128 + col;

#pragma unroll 1
    for (int ci0 = 0; ci0 < 64; ci0 += 32) {
        __syncthreads();
        // stage x[n][ci0..ci0+31][h..h+2][0..127] -> xs[r][col][ci], bf16, ci-pairs packed
#pragma unroll 1
        for (int p = half; p < 48; p += 2) {      // 24 iters/thread
            int r = p % 3;
            int cp = p / 3;                       // ci pair 0..15
            float v0 = xg[(size_t)(ci0 + 2 * cp) * 16384 + r * 128];
            float v1 = xg[(size_t)(ci0 + 2 * cp + 1) * 16384 + r * 128];
            unsigned int pk = (unsigned int)f2bf(v0) | ((unsigned int)f2bf(v1) << 16);
            *reinterpret_cast<unsigned int*>(&xs[r][col][2 * cp]) = pk;
        }
        __syncthreads();

        union Frag { uintx4 u; short8 s; };
        // A prefetch for tap 0
        Frag a[4], an[4];
        {
            const uintx4* ap = reinterpret_cast<const uintx4*>(
                wb + (size_t)(0 * 256 + coBase + li) * 64 + ci0 + quad * 8);
#pragma unroll
            for (int cf = 0; cf < 4; ++cf) a[cf].u = ap[cf * 128];
        }
#pragma unroll 1
        for (int tap = 0; tap < 9; ++tap) {
            const int kh = tap / 3;
            const int kw = tap - kh * 3;
            // B fragments: 8 x ds_read_b128 (ci-contiguous)
            Frag b[8];
            const uintx4* bp = reinterpret_cast<const uintx4*>(&xs[kh][kw + li][quad * 8]);
#pragma unroll
            for (int pf = 0; pf < 8; ++pf) b[pf].u = bp[pf * 80];   // 16 cols * 80 B = 80 uint4
            // prefetch next tap's A while MFMAs run
            if (tap < 8) {
                const uintx4* ap = reinterpret_cast<const uintx4*>(
                    wb + (size_t)((tap + 1) * 256 + coBase + li) * 64 + ci0 + quad * 8);
#pragma unroll
                for (int cf = 0; cf < 4; ++cf) an[cf].u = ap[cf * 128];
            }
#pragma unroll
            for (int cf = 0; cf < 4; ++cf)
#pragma unroll
                for (int pf = 0; pf < 8; ++pf)
                    acc[cf * 8 + pf] = __builtin_amdgcn_mfma_f32_16x16x32_bf16(
                        a[cf].s, b[pf].s, acc[cf * 8 + pf], 0, 0, 0);
#pragma unroll
            for (int cf = 0; cf < 4; ++cf) a[cf] = an[cf];
        }
    }

    // epilogue: bias + GELU + masked pixel sum + 16-lane reduce + atomic mean
    const float inv = 1.0f / (126.f * 126.f);
#pragma unroll
    for (int cf = 0; cf < 4; ++cf) {
        const floatx4 bv = *reinterpret_cast<const floatx4*>(bias + coBase + cf * 16 + quad * 4);
        floatx4 s = (floatx4){0.f, 0.f, 0.f, 0.f};
#pragma unroll
        for (int pf = 0; pf < 8; ++pf) {
            bool valid = (pf * 16 + li) < 126;
#pragma unroll
            for (int r = 0; r < 4; ++r) {
                float g = gelu_t(acc[cf * 8 + pf][r] + bv[r]);
                s[r] += valid ? g : 0.f;          // select (not multiply): kills NaN from masked cols
            }
        }
#pragma unroll
        for (int r = 0; r < 4; ++r) {
            float v = s[r];
            v += __shfl_xor(v, 1);
            v += __shfl_xor(v, 2);
            v += __shfl_xor(v, 4);
            v += __shfl_xor(v, 8);
            if (li == 0)
                atomicAdd(&out[n * 256 + coBase + cf * 16 + quad * 4 + r], v * inv);
        }
    }
}

extern "C" void kernel_launch(void* const* d_in, const int* in_sizes, int n_in,
                              void* d_out, int out_size, void* d_ws, size_t ws_size,
                              hipStream_t stream) {
    const float* x    = (const float*)d_in[0];
    const float* wgt  = (const float*)d_in[1];
    const float* bias = (const float*)d_in[2];
    float* out = (float*)d_out;
    unsigned short* wb = (unsigned short*)d_ws;   // 294912 B: Wb[tap][co][ci] bf16

    prep_kernel<<<576, 256, 0, stream>>>(wgt, out, wb);
    conv_kernel<<<64 * HO, 256, 0, stream>>>(x, bias, wb, out);
}

// Round 3
// 681.652 us; speedup vs baseline: 7.6526x; 1.2940x over previous
//
#include <hip/hip_runtime.h>

// Implicit-GEMM conv3x3(64->256, VALID) + bias + tanh-GELU + spatial mean.
// bf16 MFMA 16x16x32, fp32 accumulate.
//
// v3: 512-thread blocks (8 waves), block tile 256co x 128pix, wave tile
// 64co x 64pix (acc = 64 f32/thread, not 128 -> 2 blocks/CU with
// __launch_bounds__(512,4)). All 64 ci staged ONCE per block into a single
// 56KB LDS buffer (one __syncthreads per block; no K double-buffer needed).
// Weights pre-swizzled into fragment-linear order (wb2[frag][lane][8bf16])
// so each A fragment is ONE fully-coalesced global_load_dwordx4 (1KB
// contiguous per wave, L1/L2-resident 288KB table). B fragments are single
// ds_read_b128 with compile-time-foldable offsets (col stride 144B: reads
// ~2-way = free; staging writes b64 at 8-way but only 12 instr/thread/block).
// Epilogue: bias + GELU + masked pixel sum + 16-lane shuffle reduce +
// fp32 atomicAdd into prep-zeroed out (mean over 126*126).

typedef __attribute__((ext_vector_type(8))) short short8;
typedef __attribute__((ext_vector_type(4))) float floatx4;
typedef __attribute__((ext_vector_type(4))) unsigned int uintx4;
typedef __attribute__((ext_vector_type(2))) unsigned int uintx2;

#define HO 126
#define CIP 72   // 64 ci + 8 pad shorts: 144B col stride (16B-aligned b128; 36-bank step)

__device__ __forceinline__ unsigned int f2bf(float f) {
    unsigned int u = __float_as_uint(f);
    return (u + 0x7FFFu + ((u >> 16) & 1u)) >> 16;   // RNE
}

__device__ __forceinline__ float gelu_t(float y) {
    // gelu(y) = y * sigmoid(2*0.7978845608*(y + 0.044715 y^3))
    float p = __builtin_fmaf(0.044715f, y * y, 1.0f);
    float z2 = -2.3022084f * y * p;               // -(2*0.79788456/ln2... *log2e)
    float e = exp2f(z2);
    return y * __builtin_amdgcn_rcpf(1.0f + e);
}

__global__ __launch_bounds__(256)
void prep_kernel(const float* __restrict__ wgt, float* __restrict__ out,
                 unsigned short* __restrict__ wb2) {
    int g = blockIdx.x * 256 + threadIdx.x;
    if (g < 64 * 256) out[g] = 0.f;               // zero the atomic target
    if (g < 147456) {                             // 9 taps * 2 halves * 16 cog * 64 lane * 8
        int j    = g & 7;
        int lane = (g >> 3) & 63;
        int fc   = g >> 9;                        // 0..287
        int cog  = fc & 15;
        int half = (fc >> 4) & 1;
        int tap  = fc >> 5;
        int li = lane & 15, quad = lane >> 4;
        int co = cog * 16 + li;
        int ci = half * 32 + quad * 8 + j;
        wb2[g] = (unsigned short)f2bf(wgt[(co * 64 + ci) * 9 + tap]);
    }
}

__global__ __launch_bounds__(512, 4)
void conv_kernel(const float* __restrict__ x, const float* __restrict__ bias,
                 const unsigned short* __restrict__ wb2, float* __restrict__ out) {
    __shared__ unsigned short xs[3][130][CIP];    // 56160 B -> 2 blocks/CU

    const int bx = blockIdx.x;
    const int n = bx / HO;
    const int h = bx % HO;
    const int tid  = threadIdx.x;
    const int lane = tid & 63;
    const int wave = tid >> 6;
    const int li   = lane & 15;
    const int quad = lane >> 4;
    const int sc = wave & 3;          // co split: coBase = sc*64
    const int sp = wave >> 2;         // pix split: pixBase = sp*64
    const int coBase  = sc * 64;
    const int pixBase = sp * 64;

    // ---- stage x[n][0..63][h..h+2][0..127] -> xs[r][col][ci] bf16 (once) ----
    {
        const int col = tid & 127;
        const int g   = tid >> 7;                 // 0..3, each handles 12 of 48 cells
        const float* xg = x + (size_t)n * 64 * 16384 + h * 128 + col;
#pragma unroll
        for (int i = 0; i < 12; ++i) {
            int idx = g * 12 + i;                 // cell = r*16 + cq
            int r  = idx >> 4;
            int cq = idx & 15;                    // ci group of 4
            float v0 = xg[(size_t)(cq * 4 + 0) * 16384 + r * 128];
            float v1 = xg[(size_t)(cq * 4 + 1) * 16384 + r * 128];
            float v2 = xg[(size_t)(cq * 4 + 2) * 16384 + r * 128];
            float v3 = xg[(size_t)(cq * 4 + 3) * 16384 + r * 128];
            uintx2 pk;
            pk.x = f2bf(v0) | (f2bf(v1) << 16);
            pk.y = f2bf(v2) | (f2bf(v3) << 16);
            *reinterpret_cast<uintx2*>(&xs[r][col][cq * 4]) = pk;   // ds_write_b64
        }
    }

    floatx4 acc[16];                              // [cf 0..3][pf 0..3]
#pragma unroll
    for (int i = 0; i < 16; ++i) acc[i] = (floatx4){0.f, 0.f, 0.f, 0.f};

    __syncthreads();                              // the ONLY barrier

    union Frag { uintx4 u; short8 s; };
    // Runtime-invariant bases; all loop offsets are compile-time constants.
    const unsigned short* xbase = &xs[0][pixBase + li][0] + quad * 8;
    const unsigned short* abase = wb2 + (size_t)(sc * 4) * 512 + lane * 8;

#pragma unroll
    for (int tap = 0; tap < 9; ++tap) {
        const int kh = tap / 3;
        const int kw = tap % 3;
        Frag a[8];                                // [half][cf]
#pragma unroll
        for (int hf = 0; hf < 2; ++hf)
#pragma unroll
            for (int cf = 0; cf < 4; ++cf)
                a[hf * 4 + cf].u = *reinterpret_cast<const uintx4*>(
                    abase + (size_t)(((tap * 2 + hf) * 16) + cf) * 512);
#pragma unroll
        for (int hf = 0; hf < 2; ++hf)
#pragma unroll
            for (int pf = 0; pf < 4; ++pf) {
                Frag b;
                b.u = *reinterpret_cast<const uintx4*>(
                    xbase + (kh * 130 + kw + pf * 16) * CIP + hf * 32);  // ds_read_b128
#pragma unroll
                for (int cf = 0; cf < 4; ++cf)
                    acc[cf * 4 + pf] = __builtin_amdgcn_mfma_f32_16x16x32_bf16(
                        a[hf * 4 + cf].s, b.s, acc[cf * 4 + pf], 0, 0, 0);
            }
    }

    // ---- epilogue: bias + GELU + masked pixel sum + reduce + atomic mean ----
    const float inv = 1.0f / (126.f * 126.f);
#pragma unroll
    for (int cf = 0; cf < 4; ++cf) {
        const floatx4 bv = *reinterpret_cast<const floatx4*>(
            bias + coBase + cf * 16 + quad * 4);
        floatx4 s = (floatx4){0.f, 0.f, 0.f, 0.f};
#pragma unroll
        for (int pf = 0; pf < 4; ++pf) {
            bool valid = (pixBase + pf * 16 + li) < 126;
#pragma unroll
            for (int r = 0; r < 4; ++r) {
                float gv = gelu_t(acc[cf * 4 + pf][r] + bv[r]);
                s[r] += valid ? gv : 0.f;         // select: contains poison-col NaNs
            }
        }
#pragma unroll
        for (int r = 0; r < 4; ++r) {
            float v = s[r];
            v += __shfl_xor(v, 1);
            v += __shfl_xor(v, 2);
            v += __shfl_xor(v, 4);
            v += __shfl_xor(v, 8);
            if (li == 0)
                atomicAdd(&out[n * 256 + coBase + cf * 16 + quad * 4 + r], v * inv);
        }
    }
}

extern "C" void kernel_launch(void* const* d_in, const int* in_sizes, int n_in,
                              void* d_out, int out_size, void* d_ws, size_t ws_size,
                              hipStream_t stream) {
    const float* x    = (const float*)d_in[0];
    const float* wgt  = (const float*)d_in[1];
    const float* bias = (const float*)d_in[2];
    float* out = (float*)d_out;
    unsigned short* wb2 = (unsigned short*)d_ws;  // 294912 B, fragment-linear bf16

    prep_kernel<<<576, 256, 0, stream>>>(wgt, out, wb2);
    conv_kernel<<<64 * HO, 512, 0, stream>>>(x, bias, wb2, out);
}